// Round 5
// baseline (1759.944 us; speedup 1.0000x reference)
//
#include <hip/hip_runtime.h>
#include <hip/hip_bf16.h>

typedef __hip_bfloat16 bft;
typedef short bf8s __attribute__((ext_vector_type(8)));   // 8 bf16 (4 VGPRs)
typedef float f4 __attribute__((ext_vector_type(4)));

#define KW 5
#define NSW 2
#define EPS 1e-5f

__device__ __forceinline__ float bs2f(short s){
  union { unsigned u; float f; } v; v.u = ((unsigned)(unsigned short)s) << 16; return v.f;
}

__device__ __forceinline__ int win_start(int i, int L, int d){
  if (d <= 1){
    int s = i - NSW; if (s < 0) s = 0;
    if (i + NSW >= L) s += L - i - NSW - 1;
    return s;
  }
  int ni = i - NSW*d;
  if (ni < 0) return i % d;
  if (i + NSW*d >= L){
    int imodd = i % d;
    int a = (L / d) * d;
    int b = L - a;
    if (imodd < b) return L - b + imodd - 2*NSW*d;
    return a + imodd - KW*d;
  }
  return ni;
}
__device__ __forceinline__ int pb_start(int i, int L, int d){
  if (d <= 1){
    int s = NSW;
    if (i < NSW) s += NSW - i;
    if (i + NSW >= L) s += L - i - 1 - NSW;
    return s;
  }
  if (i - NSW*d < 0) return KW - 1 - i/d;
  if (i + NSW*d >= L) return (L - i - 1)/d;
  return NSW;
}

// ---- upfront: all 8 NAT layers' weights fp32 -> bf16, layer-contiguous ----
__global__ __launch_bounds__(256)
void k_cvt_nat(const float* __restrict__ qkv_w, const float* __restrict__ proj_w,
               const float* __restrict__ fc1_w, const float* __restrict__ fc2_w,
               bft* __restrict__ dst)
{
  for (int i = blockIdx.x*256 + threadIdx.x; i < 8*786432; i += gridDim.x*256){
    int l = i / 786432;
    int off = i - l*786432;
    float v;
    if (off < 196608) v = qkv_w[(size_t)l*196608 + off];
    else if (off < 262144) v = proj_w[(size_t)l*65536 + (off - 196608)];
    else if (off < 524288) v = fc1_w[(size_t)l*262144 + (off - 262144)];
    else v = fc2_w[(size_t)l*262144 + (off - 524288)];
    dst[i] = __float2bfloat16(v);
  }
}

__global__ __launch_bounds__(256)
void k_cvt(const float* __restrict__ src, int n, bft* __restrict__ dst)
{
  for (int i = blockIdx.x*256 + threadIdx.x; i < n; i += gridDim.x*256)
    dst[i] = __float2bfloat16(src[i]);
}

// ---- conv weight repack: OIHW fp32 -> [o][tap*256+c] bf16 (o padded) ----
__global__ __launch_bounds__(256)
void k_repack(const float* __restrict__ in, bft* __restrict__ out, int O_in)
{
  int o = blockIdx.x, c = threadIdx.x;
  #pragma unroll
  for (int tap = 0; tap < 9; tap++){
    float v = (o < O_in) ? in[((size_t)(o*256 + c))*9 + tap] : 0.f;
    out[(size_t)o*2304 + tap*256 + c] = __float2bfloat16(v);
  }
}

// ---- NCHW -> NHWC (f32) ----
__global__ __launch_bounds__(256)
void k_nchw2nhwc(const float* __restrict__ in, float* __restrict__ out,
                 int H, int W){
  int t = blockIdx.x; int c = threadIdx.x;
  int x = t % W; int y = (t / W) % H; int b = t / (W*H);
  out[(size_t)t*256 + c] = in[(((size_t)b*256 + c)*H + y)*W + x];
}

// ---- LayerNorm (C=256), one block per token; fp32 in, bf16 out ----
__global__ __launch_bounds__(256)
void k_ln(const float* __restrict__ x, const float* __restrict__ w,
          const float* __restrict__ b, bft* __restrict__ out)
{
  __shared__ float red[4];
  __shared__ float stats[2];
  int t = blockIdx.x, c = threadIdx.x;
  float v = x[(size_t)t*256 + c];
  float s = v;
  #pragma unroll
  for (int m = 32; m >= 1; m >>= 1) s += __shfl_xor(s, m, 64);
  int wave = c >> 6;
  if ((c & 63) == 0) red[wave] = s;
  __syncthreads();
  if (c == 0) stats[0] = (red[0]+red[1]+red[2]+red[3]) * (1.f/256.f);
  __syncthreads();
  float mean = stats[0];
  float dd = v - mean;
  float s2 = dd*dd;
  #pragma unroll
  for (int m = 32; m >= 1; m >>= 1) s2 += __shfl_xor(s2, m, 64);
  if ((c & 63) == 0) red[wave] = s2;
  __syncthreads();
  if (c == 0) stats[1] = (red[0]+red[1]+red[2]+red[3]) * (1.f/256.f);
  __syncthreads();
  float var = stats[1];
  out[(size_t)t*256 + c] = __float2bfloat16(dd * rsqrtf(var + EPS) * w[c] + b[c]);
}

// ======== epilogue shared by both GEMMs ========
__device__ __forceinline__ void gemm_epilogue(
    float v, int m, int n, int N, int epi, int t0, int Npost,
    void* Cv, const float* res, const float* gate,
    const float* bn_w, const float* bn_b, const float* bn_m, const float* bn_v,
    int HH, int WW)
{
  if (epi == 1){
    if (n < 256) v *= 0.17677669529663689f;
    ((bft*)Cv)[(size_t)m*N + n] = __float2bfloat16(v);
  } else if (epi == 2){
    v = 0.5f*v*(1.f + erff(v*0.70710678118654752f));
    ((bft*)Cv)[(size_t)m*N + n] = __float2bfloat16(v);
  } else if (epi == 3){
    ((float*)Cv)[(size_t)m*N + n] = res[(size_t)m*N + n] + gate[n]*v;
  } else if (epi == 4){
    float s = bn_w[n] * rsqrtf(bn_v[n] + EPS);
    ((float*)Cv)[(size_t)m*N + n] = (v - bn_m[n])*s + bn_b[n];
  } else if (epi == 5){
    float s = bn_w[n] * rsqrtf(bn_v[n] + EPS);
    float o = fmaxf((v - bn_m[n])*s + bn_b[n], 0.f);
    ((bft*)Cv)[(size_t)(t0 + m)*N + n] = __float2bfloat16(o);
  } else { // epi == 6: NCHW f32 out, n<Npost
    if (n < Npost){
      float s = bn_w[n] * rsqrtf(bn_v[n] + EPS);
      float o = fmaxf((v - bn_m[n])*s + bn_b[n], 0.f);
      int tok = t0 + m;
      int xx = tok % WW; int yy = (tok / WW) % HH; int bb = tok / (WW*HH);
      ((float*)Cv)[(((size_t)bb*Npost + n)*HH + yy)*WW + xx] = o;
    }
  }
}

// ---- fallback 64x64 direct GEMM (small M only) ----
__global__ __launch_bounds__(256)
void k_gemm(const bft* __restrict__ A, const bft* __restrict__ W,
            const float* __restrict__ bias, void* __restrict__ Cv,
            int N, int K, int epi, int t0, int Npost,
            const float* __restrict__ res, const float* __restrict__ gate,
            const float* __restrict__ bn_w, const float* __restrict__ bn_b,
            const float* __restrict__ bn_m, const float* __restrict__ bn_v,
            int HH, int WW)
{
  int tile_n = blockIdx.x * 64;
  int tile_m = blockIdx.y * 64;
  int tid = threadIdx.x;
  int wv   = tid >> 6;
  int lane = tid & 63;
  int q    = lane >> 4;
  int l15  = lane & 15;

  const bft* Arow  = A + (size_t)(tile_m + wv*16 + l15) * K + q*8;
  const bft* Wrow  = W + (size_t)(tile_n + l15) * K + q*8;

  f4 acc0 = {0.f,0.f,0.f,0.f};
  f4 acc1 = acc0, acc2 = acc0, acc3 = acc0;

  for (int k0 = 0; k0 < K; k0 += 32){
    bf8s a  = *(const bf8s*)(Arow + k0);
    bf8s b0 = *(const bf8s*)(Wrow + k0);
    bf8s b1 = *(const bf8s*)(Wrow + (size_t)16*K + k0);
    bf8s b2 = *(const bf8s*)(Wrow + (size_t)32*K + k0);
    bf8s b3 = *(const bf8s*)(Wrow + (size_t)48*K + k0);
    acc0 = __builtin_amdgcn_mfma_f32_16x16x32_bf16(a, b0, acc0, 0, 0, 0);
    acc1 = __builtin_amdgcn_mfma_f32_16x16x32_bf16(a, b1, acc1, 0, 0, 0);
    acc2 = __builtin_amdgcn_mfma_f32_16x16x32_bf16(a, b2, acc2, 0, 0, 0);
    acc3 = __builtin_amdgcn_mfma_f32_16x16x32_bf16(a, b3, acc3, 0, 0, 0);
  }

  f4 accs[4] = {acc0, acc1, acc2, acc3};
  #pragma unroll
  for (int nt = 0; nt < 4; nt++){
    int n = tile_n + nt*16 + l15;
    float bs = (epi == 6 && n >= Npost) ? 0.f : bias[n];
    #pragma unroll
    for (int r = 0; r < 4; r++){
      int m = tile_m + wv*16 + q*4 + r;
      gemm_epilogue(accs[nt][r] + bs, m, n, N, epi, t0, Npost,
                    Cv, res, gate, bn_w, bn_b, bn_m, bn_v, HH, WW);
    }
  }
}

// ---- 128x128 LDS-staged double-buffered MFMA GEMM ----
// tap=0: A is Mloc x K bf16 row-major.
// tap=1: implicit im2col — A is bf16 NHWC (C=256), K=2304, token row = tile_m+row,
//        k = tap9*256 + c, with SAME zero padding. Requires M%128==0, N%128==0, K%32==0.
__global__ __launch_bounds__(256)
void k_gemm128(const bft* __restrict__ A, const bft* __restrict__ Wt,
               const float* __restrict__ bias, void* __restrict__ Cv,
               int N, int K, int epi, int tap, int t0, int Npost,
               const float* __restrict__ res, const float* __restrict__ gate,
               const float* __restrict__ bn_w, const float* __restrict__ bn_b,
               const float* __restrict__ bn_m, const float* __restrict__ bn_v,
               int HH, int WW)
{
  __shared__ short As[2][5120];   // 128 rows x 40 (stride-pad: 2-way banks)
  __shared__ short Bs[2][5120];

  const int tid = threadIdx.x;
  const int tile_n = blockIdx.x * 128;
  const int tile_m = blockIdx.y * 128;
  const int w = tid >> 6, lane = tid & 63, q = lane >> 4, l15 = lane & 15;
  const int wm = w >> 1, wn = w & 1;

  // staging geometry: thread covers A rows (ar0, ar0+64) chunk ac0, same for B
  const int ar0 = tid >> 2;
  const int ac0 = (tid & 3) * 8;        // k-offset within BK in bf16

  const bft* aptr0 = A + (size_t)(tile_m + ar0) * K + ac0;
  const bft* aptr1 = aptr0 + (size_t)64 * K;
  const bft* bptr0 = Wt + (size_t)(tile_n + ar0) * K + ac0;
  const bft* bptr1 = bptr0 + (size_t)64 * K;

  // tap-mode per-row token decomposition (iteration-invariant)
  int ax0=0, ay0=0, ab0=0, ax1=0, ay1=0, ab1=0;
  if (tap){
    int tok0 = tile_m + ar0;
    ax0 = tok0 % WW; ay0 = (tok0 / WW) % HH; ab0 = tok0 / (WW*HH);
    int tok1 = tok0 + 64;
    ax1 = tok1 % WW; ay1 = (tok1 / WW) % HH; ab1 = tok1 / (WW*HH);
  }

  f4 acc[4][4];
  #pragma unroll
  for (int i = 0; i < 4; i++)
    #pragma unroll
    for (int j = 0; j < 4; j++) acc[i][j] = (f4){0.f,0.f,0.f,0.f};

  const int iters = K >> 5;

  auto loadA = [&](int k0, bf8s &v0, bf8s &v1){
    if (!tap){
      v0 = *(const bf8s*)(aptr0 + k0);
      v1 = *(const bf8s*)(aptr1 + k0);
    } else {
      int kk = k0 + ac0;
      int tp = kk >> 8;
      int c  = kk & 255;
      int ty = tp / 3;
      int ky = ty - 1, kx = tp - ty*3 - 1;
      bf8s z; 
      #pragma unroll
      for (int e = 0; e < 8; e++) z[e] = 0;
      {
        int yy = ay0 + ky, xx = ax0 + kx;
        v0 = (yy >= 0 && yy < HH && xx >= 0 && xx < WW)
           ? *(const bf8s*)(A + ((((size_t)ab0*HH + yy)*WW + xx) << 8) + c) : z;
      }
      {
        int yy = ay1 + ky, xx = ax1 + kx;
        v1 = (yy >= 0 && yy < HH && xx >= 0 && xx < WW)
           ? *(const bf8s*)(A + ((((size_t)ab1*HH + yy)*WW + xx) << 8) + c) : z;
      }
    }
  };

  // prologue: stage k0=0 into buffer 0
  {
    bf8s a0, a1, b0, b1;
    loadA(0, a0, a1);
    b0 = *(const bf8s*)(bptr0);
    b1 = *(const bf8s*)(bptr1);
    *(bf8s*)(&As[0][ar0*40 + ac0])      = a0;
    *(bf8s*)(&As[0][(ar0+64)*40 + ac0]) = a1;
    *(bf8s*)(&Bs[0][ar0*40 + ac0])      = b0;
    *(bf8s*)(&Bs[0][(ar0+64)*40 + ac0]) = b1;
  }
  __syncthreads();

  for (int it = 0; it < iters; it++){
    int cur = it & 1;
    bf8s na0, na1, nb0, nb1;
    bool have = (it + 1 < iters);
    if (have){
      int k0n = (it + 1) << 5;
      loadA(k0n, na0, na1);
      nb0 = *(const bf8s*)(bptr0 + k0n);
      nb1 = *(const bf8s*)(bptr1 + k0n);
    }

    bf8s af[4], bf[4];
    #pragma unroll
    for (int mi = 0; mi < 4; mi++)
      af[mi] = *(const bf8s*)(&As[cur][(wm*64 + mi*16 + l15)*40 + q*8]);
    #pragma unroll
    for (int ni = 0; ni < 4; ni++)
      bf[ni] = *(const bf8s*)(&Bs[cur][(wn*64 + ni*16 + l15)*40 + q*8]);
    #pragma unroll
    for (int mi = 0; mi < 4; mi++)
      #pragma unroll
      for (int ni = 0; ni < 4; ni++)
        acc[mi][ni] = __builtin_amdgcn_mfma_f32_16x16x32_bf16(af[mi], bf[ni], acc[mi][ni], 0, 0, 0);

    if (have){
      int nxt = cur ^ 1;
      *(bf8s*)(&As[nxt][ar0*40 + ac0])      = na0;
      *(bf8s*)(&As[nxt][(ar0+64)*40 + ac0]) = na1;
      *(bf8s*)(&Bs[nxt][ar0*40 + ac0])      = nb0;
      *(bf8s*)(&Bs[nxt][(ar0+64)*40 + ac0]) = nb1;
    }
    __syncthreads();
  }

  #pragma unroll
  for (int ni = 0; ni < 4; ni++){
    int n = tile_n + wn*64 + ni*16 + l15;
    float bs = (epi == 6 && n >= Npost) ? 0.f : bias[n];
    #pragma unroll
    for (int mi = 0; mi < 4; mi++){
      #pragma unroll
      for (int r = 0; r < 4; r++){
        int m = tile_m + wm*64 + mi*16 + q*4 + r;
        gemm_epilogue(acc[mi][ni][r] + bs, m, n, N, epi, t0, Npost,
                      Cv, res, gate, bn_w, bn_b, bn_m, bn_v, HH, WW);
      }
    }
  }
}

// ---- neighborhood attention: one THREAD per (token, head) ----
__global__ __launch_bounds__(256)
void k_attn(const bft* __restrict__ qkv, const float* __restrict__ rpb,
            bft* __restrict__ o, int Hh, int Ww, int d)
{
  int gid  = blockIdx.x*256 + threadIdx.x;
  int head = gid & 7;
  int t    = gid >> 3;
  int j = t % Ww; int i = (t / Ww) % Hh;
  int base = (t / (Ww*Hh)) * Hh * Ww;

  const bft* qp = qkv + (size_t)t*768 + head*32;
  float q[32];
  #pragma unroll
  for (int u = 0; u < 4; u++){
    bf8s qv = *(const bf8s*)(qp + u*8);
    #pragma unroll
    for (int e = 0; e < 8; e++) q[u*8+e] = bs2f(qv[e]);
  }

  int is = win_start(i, Hh, d), js = win_start(j, Ww, d);
  int bi = pb_start(i, Hh, d), bj = pb_start(j, Ww, d);

  float logits[25];
  int tns[25];
  #pragma unroll
  for (int x = 0; x < 5; x++){
    int rowb = base + (is + x*d)*Ww;
    #pragma unroll
    for (int y = 0; y < 5; y++){
      int tn = rowb + js + y*d;
      tns[x*5+y] = tn;
      const bft* kp = qkv + (size_t)tn*768 + 256 + head*32;
      float s = 0.f;
      #pragma unroll
      for (int u = 0; u < 4; u++){
        bf8s kv = *(const bf8s*)(kp + u*8);
        #pragma unroll
        for (int e = 0; e < 8; e++) s += q[u*8+e] * bs2f(kv[e]);
      }
      logits[x*5+y] = s + rpb[head*81 + (bi + x)*9 + (bj + y)];
    }
  }

  float mx = logits[0];
  #pragma unroll
  for (int p = 1; p < 25; p++) mx = fmaxf(mx, logits[p]);
  float ssum = 0.f;
  #pragma unroll
  for (int p = 0; p < 25; p++){ float e = __expf(logits[p] - mx); logits[p] = e; ssum += e; }
  float inv = 1.f / ssum;

  float acc[32];
  #pragma unroll
  for (int e = 0; e < 32; e++) acc[e] = 0.f;
  #pragma unroll
  for (int p = 0; p < 25; p++){
    float wgt = logits[p] * inv;
    const bft* vp = qkv + (size_t)tns[p]*768 + 512 + head*32;
    #pragma unroll
    for (int u = 0; u < 4; u++){
      bf8s vv = *(const bf8s*)(vp + u*8);
      #pragma unroll
      for (int e = 0; e < 8; e++) acc[u*8+e] += wgt * bs2f(vv[e]);
    }
  }

  bft* op = o + (size_t)t*256 + head*32;
  #pragma unroll
  for (int u = 0; u < 4; u++){
    bf8s ov;
    #pragma unroll
    for (int e = 0; e < 8; e++){
      bft h = __float2bfloat16(acc[u*8+e]);
      union { bft b; short s; } cv; cv.b = h;
      ov[e] = cv.s;
    }
    *(bf8s*)(op + u*8) = ov;
  }
}

// ---- fuse-cat: A[t][0..255]=feat(NCHW f32), A[t][256..511]=bilinear(Xprev) ----
__global__ __launch_bounds__(256)
void k_fusecat(const float* __restrict__ feat, const float* __restrict__ xprev,
               bft* __restrict__ out, int h, int w, int H2, int W2)
{
  int t = blockIdx.x; int c = threadIdx.x;
  int x = t % W2; int y = (t / W2) % H2; int b = t / (W2*H2);
  out[(size_t)t*512 + c] = __float2bfloat16(feat[(((size_t)b*256 + c)*H2 + y)*W2 + x]);
  float fy = (float)y * (float)(h-1) / (float)(H2-1);
  float fx = (float)x * (float)(w-1) / (float)(W2-1);
  int y0 = (int)floorf(fy); int y1 = min(y0+1, h-1); float wy = fy - (float)y0;
  int x0 = (int)floorf(fx); int x1 = min(x0+1, w-1); float wx = fx - (float)x0;
  const float* basep = xprev + (size_t)b*h*w*256;
  float a  = basep[((size_t)y0*w + x0)*256 + c];
  float bb = basep[((size_t)y0*w + x1)*256 + c];
  float cc = basep[((size_t)y1*w + x0)*256 + c];
  float e  = basep[((size_t)y1*w + x1)*256 + c];
  float u = a*(1.f-wy)*(1.f-wx) + bb*(1.f-wy)*wx + cc*wy*(1.f-wx) + e*wy*wx;
  out[(size_t)t*512 + 256 + c] = __float2bfloat16(u);
}

extern "C" void kernel_launch(void* const* d_in, const int* in_sizes, int n_in,
                              void* d_out, int out_size, void* d_ws, size_t ws_size,
                              hipStream_t stream)
{
  (void)in_sizes; (void)n_in; (void)out_size; (void)ws_size;
  const float* x0     = (const float*)d_in[0];
  const float* x1     = (const float*)d_in[1];
  const float* x2     = (const float*)d_in[2];
  const float* x3     = (const float*)d_in[3];
  const float* ln1_w  = (const float*)d_in[4];
  const float* ln1_b  = (const float*)d_in[5];
  const float* qkv_w  = (const float*)d_in[6];
  const float* qkv_b  = (const float*)d_in[7];
  const float* rpb    = (const float*)d_in[8];
  const float* proj_w = (const float*)d_in[9];
  const float* proj_b = (const float*)d_in[10];
  const float* ln2_w  = (const float*)d_in[11];
  const float* ln2_b  = (const float*)d_in[12];
  const float* fc1_w  = (const float*)d_in[13];
  const float* fc1_b  = (const float*)d_in[14];
  const float* fc2_w  = (const float*)d_in[15];
  const float* fc2_b  = (const float*)d_in[16];
  const float* g1     = (const float*)d_in[17];
  const float* g2     = (const float*)d_in[18];
  const float* fuse_w = (const float*)d_in[19];
  const float* fuse_b = (const float*)d_in[20];
  const float* fbn_w  = (const float*)d_in[21];
  const float* fbn_b  = (const float*)d_in[22];
  const float* fbn_m  = (const float*)d_in[23];
  const float* fbn_v  = (const float*)d_in[24];
  const float* lc1_w  = (const float*)d_in[25];
  const float* lc1_b  = (const float*)d_in[26];
  const float* lbn1_w = (const float*)d_in[27];
  const float* lbn1_b = (const float*)d_in[28];
  const float* lbn1_m = (const float*)d_in[29];
  const float* lbn1_v = (const float*)d_in[30];
  const float* lc2_w  = (const float*)d_in[31];
  const float* lc2_b  = (const float*)d_in[32];
  const float* lbn2_w = (const float*)d_in[33];
  const float* lbn2_b = (const float*)d_in[34];
  const float* lbn2_m = (const float*)d_in[35];
  const float* lbn2_v = (const float*)d_in[36];

  // ---- workspace layout (bytes), total 58,589,184 (<= proven 58,884,096) ----
  char* ws = (char*)d_ws;
  float* X  = (float*)ws;                      // 12288*256 f32   = 12,582,912
  bft*   B1 = (bft*)(ws + 12582912);           // 12288*256 bf16  =  6,291,456
  bft*   B2 = (bft*)(ws + 18874368);           // 12288*1024 bf16 = 25,165,824
  bft*   IM = B2;                              // fuse-cat buffer aliases B2
  bft*   Xb = B2;                              // conv input bf16 aliases B2 (3,145,728 el)
  bft*   W_C2 = B2 + 4194304;                  // 128*2304 el inside B2's tail
  bft*   WB = (bft*)(ws + 44040192);           // static weights

  bft* W_NAT  = WB;                            // 8 * 786432
  bft* W_FUSE = WB + 6291456;                  // 3 * 131072
  bft* W_C1   = WB + 6684672;                  // 256*2304

  // upfront weight conversion
  k_cvt_nat<<<2048, 256, 0, stream>>>(qkv_w, proj_w, fc1_w, fc2_w, W_NAT);
  k_cvt<<<512, 256, 0, stream>>>(fuse_w, 393216, W_FUSE);
  k_repack<<<256, 256, 0, stream>>>(lc1_w, W_C1, 256);

  auto gemm = [&](const bft* A, const bft* W, const float* bias, void* C,
                  int Mloc, int N, int K, int epi, int tap, int t0, int Npost,
                  const float* res, const float* gate,
                  const float* bw, const float* bb, const float* bm, const float* bv,
                  int HH, int WW){
    if ((Mloc % 128) == 0 && (N % 128) == 0){
      dim3 g(N/128, Mloc/128);
      k_gemm128<<<g, 256, 0, stream>>>(A, W, bias, C, N, K, epi, tap, t0, Npost,
                                       res, gate, bw, bb, bm, bv, HH, WW);
    } else {
      dim3 g(N/64, Mloc/64);
      k_gemm<<<g, 256, 0, stream>>>(A, W, bias, C, N, K, epi, t0, Npost,
                                    res, gate, bw, bb, bm, bv, HH, WW);
    }
  };

  auto nat = [&](int l, int d, int Hh, int Ww){
    int T = 4*Hh*Ww;
    bft* wQKV  = W_NAT + (size_t)l*786432;
    bft* wPROJ = wQKV + 196608;
    bft* wFC1  = wQKV + 262144;
    bft* wFC2  = wQKV + 524288;
    k_ln<<<T, 256, 0, stream>>>(X, ln1_w + l*256, ln1_b + l*256, B1);
    gemm(B1, wQKV, qkv_b + l*768, B2, T, 768, 256, 1, 0, 0, 0,
         nullptr, nullptr, nullptr, nullptr, nullptr, nullptr, 0, 0);
    k_attn<<<T*8/256, 256, 0, stream>>>(B2, rpb + l*648, B1, Hh, Ww, d);
    gemm(B1, wPROJ, proj_b + l*256, X, T, 256, 256, 3, 0, 0, 0,
         X, g1 + l*256, nullptr, nullptr, nullptr, nullptr, 0, 0);
    k_ln<<<T, 256, 0, stream>>>(X, ln2_w + l*256, ln2_b + l*256, B1);
    gemm(B1, wFC1, fc1_b + l*1024, B2, T, 1024, 256, 2, 0, 0, 0,
         nullptr, nullptr, nullptr, nullptr, nullptr, nullptr, 0, 0);
    gemm(B2, wFC2, fc2_b + l*256, X, T, 256, 1024, 3, 0, 0, 0,
         X, g2 + l*256, nullptr, nullptr, nullptr, nullptr, 0, 0);
  };

  auto fuse = [&](int i, const float* feat, int h, int w, int H2, int W2){
    int Tn = 4*H2*W2;
    k_fusecat<<<Tn, 256, 0, stream>>>(feat, X, IM, h, w, H2, W2);
    gemm(IM, W_FUSE + (size_t)i*131072, fuse_b + i*256, X, Tn, 256, 512, 4, 0, 0, 0,
         nullptr, nullptr, fbn_w + i*256, fbn_b + i*256, fbn_m + i*256, fbn_v + i*256, 0, 0);
  };

  // level 3: 8x6
  k_nchw2nhwc<<<4*8*6, 256, 0, stream>>>(x3, X, 8, 6);
  nat(0, 1, 8, 6);
  nat(1, 1, 8, 6);
  fuse(0, x2, 8, 6, 16, 12);
  // level 2: 16x12
  nat(2, 2, 16, 12);
  nat(3, 2, 16, 12);
  fuse(1, x1, 16, 12, 32, 24);
  // level 1: 32x24
  nat(4, 4, 32, 24);
  nat(5, 4, 32, 24);
  fuse(2, x0, 32, 24, 64, 48);
  // level 0: 64x48
  nat(6, 8, 64, 48);
  nat(7, 8, 64, 48);

  // ---- convs: implicit-im2col MFMA GEMMs ----
  k_cvt<<<3072, 256, 0, stream>>>(X, 3145728, Xb);           // conv1 input bf16
  k_repack<<<128, 256, 0, stream>>>(lc2_w, W_C2, 17);        // padded to N=128
  // conv1: M=12288, N=256, K=2304, tap-mode from Xb, BN+ReLU -> B1 (bf16 NHWC)
  gemm(Xb, W_C1, lc1_b, B1, 12288, 256, 2304, 5, 1, 0, 0,
       nullptr, nullptr, lbn1_w, lbn1_b, lbn1_m, lbn1_v, 64, 48);
  // conv2: M=12288, N=128(pad), K=2304, tap-mode from B1 -> d_out f32 NCHW (n<17)
  gemm(B1, W_C2, lc2_b, d_out, 12288, 128, 2304, 6, 1, 0, 17,
       nullptr, nullptr, lbn2_w, lbn2_b, lbn2_m, lbn2_v, 64, 48);
}

// Round 6
// 1183.703 us; speedup vs baseline: 1.4868x; 1.4868x over previous
//
#include <hip/hip_runtime.h>
#include <hip/hip_bf16.h>

typedef __hip_bfloat16 bft;
typedef short bf8s __attribute__((ext_vector_type(8)));   // 8 bf16 (4 VGPRs)
typedef float f4 __attribute__((ext_vector_type(4)));

#define KW 5
#define NSW 2
#define EPS 1e-5f

__device__ __forceinline__ float bs2f(short s){
  union { unsigned u; float f; } v; v.u = ((unsigned)(unsigned short)s) << 16; return v.f;
}

__device__ __forceinline__ int win_start(int i, int L, int d){
  if (d <= 1){
    int s = i - NSW; if (s < 0) s = 0;
    if (i + NSW >= L) s += L - i - NSW - 1;
    return s;
  }
  int ni = i - NSW*d;
  if (ni < 0) return i % d;
  if (i + NSW*d >= L){
    int imodd = i % d;
    int a = (L / d) * d;
    int b = L - a;
    if (imodd < b) return L - b + imodd - 2*NSW*d;
    return a + imodd - KW*d;
  }
  return ni;
}
__device__ __forceinline__ int pb_start(int i, int L, int d){
  if (d <= 1){
    int s = NSW;
    if (i < NSW) s += NSW - i;
    if (i + NSW >= L) s += L - i - 1 - NSW;
    return s;
  }
  if (i - NSW*d < 0) return KW - 1 - i/d;
  if (i + NSW*d >= L) return (L - i - 1)/d;
  return NSW;
}

// ---- upfront: all 8 NAT layers' weights fp32 -> bf16, layer-contiguous ----
__global__ __launch_bounds__(256)
void k_cvt_nat(const float* __restrict__ qkv_w, const float* __restrict__ proj_w,
               const float* __restrict__ fc1_w, const float* __restrict__ fc2_w,
               bft* __restrict__ dst)
{
  for (int i = blockIdx.x*256 + threadIdx.x; i < 8*786432; i += gridDim.x*256){
    int l = i / 786432;
    int off = i - l*786432;
    float v;
    if (off < 196608) v = qkv_w[(size_t)l*196608 + off];
    else if (off < 262144) v = proj_w[(size_t)l*65536 + (off - 196608)];
    else if (off < 524288) v = fc1_w[(size_t)l*262144 + (off - 262144)];
    else v = fc2_w[(size_t)l*262144 + (off - 524288)];
    dst[i] = __float2bfloat16(v);
  }
}

__global__ __launch_bounds__(256)
void k_cvt(const float* __restrict__ src, int n, bft* __restrict__ dst)
{
  for (int i = blockIdx.x*256 + threadIdx.x; i < n; i += gridDim.x*256)
    dst[i] = __float2bfloat16(src[i]);
}

// ---- conv weight repack: OIHW fp32 -> [o][tap*256+c] bf16 (o padded) ----
__global__ __launch_bounds__(256)
void k_repack(const float* __restrict__ in, bft* __restrict__ out, int O_in)
{
  int o = blockIdx.x, c = threadIdx.x;
  #pragma unroll
  for (int tap = 0; tap < 9; tap++){
    float v = (o < O_in) ? in[((size_t)(o*256 + c))*9 + tap] : 0.f;
    out[(size_t)o*2304 + tap*256 + c] = __float2bfloat16(v);
  }
}

// ---- NCHW -> NHWC (f32) ----
__global__ __launch_bounds__(256)
void k_nchw2nhwc(const float* __restrict__ in, float* __restrict__ out,
                 int H, int W){
  int t = blockIdx.x; int c = threadIdx.x;
  int x = t % W; int y = (t / W) % H; int b = t / (W*H);
  out[(size_t)t*256 + c] = in[(((size_t)b*256 + c)*H + y)*W + x];
}

// ---- LayerNorm (C=256), one block per token; fp32 in, bf16 out ----
__global__ __launch_bounds__(256)
void k_ln(const float* __restrict__ x, const float* __restrict__ w,
          const float* __restrict__ b, bft* __restrict__ out)
{
  __shared__ float red[4];
  __shared__ float stats[2];
  int t = blockIdx.x, c = threadIdx.x;
  float v = x[(size_t)t*256 + c];
  float s = v;
  #pragma unroll
  for (int m = 32; m >= 1; m >>= 1) s += __shfl_xor(s, m, 64);
  int wave = c >> 6;
  if ((c & 63) == 0) red[wave] = s;
  __syncthreads();
  if (c == 0) stats[0] = (red[0]+red[1]+red[2]+red[3]) * (1.f/256.f);
  __syncthreads();
  float mean = stats[0];
  float dd = v - mean;
  float s2 = dd*dd;
  #pragma unroll
  for (int m = 32; m >= 1; m >>= 1) s2 += __shfl_xor(s2, m, 64);
  if ((c & 63) == 0) red[wave] = s2;
  __syncthreads();
  if (c == 0) stats[1] = (red[0]+red[1]+red[2]+red[3]) * (1.f/256.f);
  __syncthreads();
  float var = stats[1];
  out[(size_t)t*256 + c] = __float2bfloat16(dd * rsqrtf(var + EPS) * w[c] + b[c]);
}

// ======== shared epilogue ========
// epi: 1 qkv-scale(n<256)->bf16; 2 gelu->bf16; 3 res+gate->f32;
//      4 fuse-BN->f32; 5 conv-BN+ReLU->bf16; 6 conv-BN+ReLU->f32 NCHW (n<Npost);
//      7 res+gate->bf16
__device__ __forceinline__ void gemm_epilogue(
    float v, int m, int n, int N, int epi, int t0, int Npost,
    void* Cv, const float* res, const float* gate,
    const float* bn_w, const float* bn_b, const float* bn_m, const float* bn_v,
    int HH, int WW)
{
  if (epi == 1){
    if (n < 256) v *= 0.17677669529663689f;
    ((bft*)Cv)[(size_t)m*N + n] = __float2bfloat16(v);
  } else if (epi == 2){
    v = 0.5f*v*(1.f + erff(v*0.70710678118654752f));
    ((bft*)Cv)[(size_t)m*N + n] = __float2bfloat16(v);
  } else if (epi == 3){
    ((float*)Cv)[(size_t)m*N + n] = res[(size_t)m*N + n] + gate[n]*v;
  } else if (epi == 4){
    float s = bn_w[n] * rsqrtf(bn_v[n] + EPS);
    ((float*)Cv)[(size_t)m*N + n] = (v - bn_m[n])*s + bn_b[n];
  } else if (epi == 5){
    float s = bn_w[n] * rsqrtf(bn_v[n] + EPS);
    float o = fmaxf((v - bn_m[n])*s + bn_b[n], 0.f);
    ((bft*)Cv)[(size_t)(t0 + m)*N + n] = __float2bfloat16(o);
  } else if (epi == 6){
    if (n < Npost){
      float s = bn_w[n] * rsqrtf(bn_v[n] + EPS);
      float o = fmaxf((v - bn_m[n])*s + bn_b[n], 0.f);
      int tok = t0 + m;
      int xx = tok % WW; int yy = (tok / WW) % HH; int bb = tok / (WW*HH);
      ((float*)Cv)[(((size_t)bb*Npost + n)*HH + yy)*WW + xx] = o;
    }
  } else { // epi == 7: residual+gate, bf16 out
    ((bft*)Cv)[(size_t)m*N + n] = __float2bfloat16(res[(size_t)m*N + n] + gate[n]*v);
  }
}

// ---- 128x128 LDS-staged double-buffered MFMA GEMM (big grids only) ----
__global__ __launch_bounds__(256)
void k_gemm128(const bft* __restrict__ A, const bft* __restrict__ Wt,
               const float* __restrict__ bias, void* __restrict__ Cv,
               int N, int K, int epi, int t0, int Npost,
               const float* __restrict__ res, const float* __restrict__ gate,
               const float* __restrict__ bn_w, const float* __restrict__ bn_b,
               const float* __restrict__ bn_m, const float* __restrict__ bn_v,
               int HH, int WW)
{
  __shared__ short As[2][5120];   // 128 rows x 40
  __shared__ short Bs[2][5120];

  const int tid = threadIdx.x;
  const int tile_n = blockIdx.x * 128;
  const int tile_m = blockIdx.y * 128;
  const int w = tid >> 6, lane = tid & 63, q = lane >> 4, l15 = lane & 15;
  const int wm = w >> 1, wn = w & 1;

  const int ar0 = tid >> 2;
  const int ac0 = (tid & 3) * 8;

  const bft* aptr0 = A + (size_t)(tile_m + ar0) * K + ac0;
  const bft* aptr1 = aptr0 + (size_t)64 * K;
  const bft* bptr0 = Wt + (size_t)(tile_n + ar0) * K + ac0;
  const bft* bptr1 = bptr0 + (size_t)64 * K;

  f4 acc[4][4];
  #pragma unroll
  for (int i = 0; i < 4; i++)
    #pragma unroll
    for (int j = 0; j < 4; j++) acc[i][j] = (f4){0.f,0.f,0.f,0.f};

  const int iters = K >> 5;

  {
    bf8s a0 = *(const bf8s*)(aptr0);
    bf8s a1 = *(const bf8s*)(aptr1);
    bf8s b0 = *(const bf8s*)(bptr0);
    bf8s b1 = *(const bf8s*)(bptr1);
    *(bf8s*)(&As[0][ar0*40 + ac0])      = a0;
    *(bf8s*)(&As[0][(ar0+64)*40 + ac0]) = a1;
    *(bf8s*)(&Bs[0][ar0*40 + ac0])      = b0;
    *(bf8s*)(&Bs[0][(ar0+64)*40 + ac0]) = b1;
  }
  __syncthreads();

  for (int it = 0; it < iters; it++){
    int cur = it & 1;
    bf8s na0, na1, nb0, nb1;
    bool have = (it + 1 < iters);
    if (have){
      int k0n = (it + 1) << 5;
      na0 = *(const bf8s*)(aptr0 + k0n);
      na1 = *(const bf8s*)(aptr1 + k0n);
      nb0 = *(const bf8s*)(bptr0 + k0n);
      nb1 = *(const bf8s*)(bptr1 + k0n);
    }

    bf8s af[4], bf[4];
    #pragma unroll
    for (int mi = 0; mi < 4; mi++)
      af[mi] = *(const bf8s*)(&As[cur][(wm*64 + mi*16 + l15)*40 + q*8]);
    #pragma unroll
    for (int ni = 0; ni < 4; ni++)
      bf[ni] = *(const bf8s*)(&Bs[cur][(wn*64 + ni*16 + l15)*40 + q*8]);
    #pragma unroll
    for (int mi = 0; mi < 4; mi++)
      #pragma unroll
      for (int ni = 0; ni < 4; ni++)
        acc[mi][ni] = __builtin_amdgcn_mfma_f32_16x16x32_bf16(af[mi], bf[ni], acc[mi][ni], 0, 0, 0);

    if (have){
      int nxt = cur ^ 1;
      *(bf8s*)(&As[nxt][ar0*40 + ac0])      = na0;
      *(bf8s*)(&As[nxt][(ar0+64)*40 + ac0]) = na1;
      *(bf8s*)(&Bs[nxt][ar0*40 + ac0])      = nb0;
      *(bf8s*)(&Bs[nxt][(ar0+64)*40 + ac0]) = nb1;
    }
    __syncthreads();
  }

  #pragma unroll
  for (int ni = 0; ni < 4; ni++){
    int n = tile_n + wn*64 + ni*16 + l15;
    float bs = (epi == 6 && n >= Npost) ? 0.f : bias[n];
    #pragma unroll
    for (int mi = 0; mi < 4; mi++){
      #pragma unroll
      for (int r = 0; r < 4; r++){
        int m = tile_m + wm*64 + mi*16 + q*4 + r;
        gemm_epilogue(acc[mi][ni][r] + bs, m, n, N, epi, t0, Npost,
                      Cv, res, gate, bn_w, bn_b, bn_m, bn_v, HH, WW);
      }
    }
  }
}

// ---- 64x64 BK=64 LDS-staged double-buffered MFMA GEMM (high-occupancy) ----
// tap=1: implicit im2col from bf16 NHWC (C=256, K=2304, SAME padding)
__global__ __launch_bounds__(256, 4)
void k_gemm64L(const bft* __restrict__ A, const bft* __restrict__ Wt,
               const float* __restrict__ bias, void* __restrict__ Cv,
               int N, int K, int epi, int tap, int t0, int Npost,
               const float* __restrict__ res, const float* __restrict__ gate,
               const float* __restrict__ bn_w, const float* __restrict__ bn_b,
               const float* __restrict__ bn_m, const float* __restrict__ bn_v,
               int HH, int WW)
{
  __shared__ short As[2][4608];   // 64 rows x 72 (64 data + 8 pad)
  __shared__ short Bs[2][4608];

  const int tid = threadIdx.x;
  const int tile_n = blockIdx.x * 64;
  const int tile_m = blockIdx.y * 64;
  const int w = tid >> 6, lane = tid & 63, q = lane >> 4, l15 = lane & 15;

  const int ra = tid >> 2;            // staging row 0..63
  const int cb = (tid & 3) * 8;       // short-offset of first chunk

  const bft* aptr = A + (size_t)(tile_m + ra) * K + cb;
  const bft* bptr = Wt + (size_t)(tile_n + ra) * K + cb;

  int ax = 0, ay = 0, ab = 0;
  if (tap){
    int tok = tile_m + ra;
    ax = tok % WW; ay = (tok / WW) % HH; ab = tok / (WW*HH);
  }

  f4 acc[4];
  #pragma unroll
  for (int i = 0; i < 4; i++) acc[i] = (f4){0.f,0.f,0.f,0.f};

  const int iters = K >> 6;

  auto loadA2 = [&](int k0, bf8s &v0, bf8s &v1){
    if (!tap){
      v0 = *(const bf8s*)(aptr + k0);
      v1 = *(const bf8s*)(aptr + k0 + 32);
    } else {
      bf8s z;
      #pragma unroll
      for (int e = 0; e < 8; e++) z[e] = 0;
      #pragma unroll
      for (int h = 0; h < 2; h++){
        int kk = k0 + cb + h*32;
        int tp = kk >> 8;
        int c  = kk & 255;
        int ty = tp / 3;
        int ky = ty - 1, kx = tp - ty*3 - 1;
        int yy = ay + ky, xx = ax + kx;
        bf8s r = (yy >= 0 && yy < HH && xx >= 0 && xx < WW)
               ? *(const bf8s*)(A + ((((size_t)ab*HH + yy)*WW + xx) << 8) + c) : z;
        if (h == 0) v0 = r; else v1 = r;
      }
    }
  };

  {
    bf8s a0, a1;
    loadA2(0, a0, a1);
    bf8s b0 = *(const bf8s*)(bptr);
    bf8s b1 = *(const bf8s*)(bptr + 32);
    *(bf8s*)(&As[0][ra*72 + cb])      = a0;
    *(bf8s*)(&As[0][ra*72 + cb + 32]) = a1;
    *(bf8s*)(&Bs[0][ra*72 + cb])      = b0;
    *(bf8s*)(&Bs[0][ra*72 + cb + 32]) = b1;
  }
  __syncthreads();

  for (int it = 0; it < iters; it++){
    int cur = it & 1;
    bf8s na0, na1, nb0, nb1;
    bool have = (it + 1 < iters);
    if (have){
      int k0n = (it + 1) << 6;
      loadA2(k0n, na0, na1);
      nb0 = *(const bf8s*)(bptr + k0n);
      nb1 = *(const bf8s*)(bptr + k0n + 32);
    }

    bf8s af[2], bfr[4][2];
    #pragma unroll
    for (int kc = 0; kc < 2; kc++)
      af[kc] = *(const bf8s*)(&As[cur][(w*16 + l15)*72 + kc*32 + q*8]);
    #pragma unroll
    for (int ni = 0; ni < 4; ni++)
      #pragma unroll
      for (int kc = 0; kc < 2; kc++)
        bfr[ni][kc] = *(const bf8s*)(&Bs[cur][(ni*16 + l15)*72 + kc*32 + q*8]);
    #pragma unroll
    for (int kc = 0; kc < 2; kc++)
      #pragma unroll
      for (int ni = 0; ni < 4; ni++)
        acc[ni] = __builtin_amdgcn_mfma_f32_16x16x32_bf16(af[kc], bfr[ni][kc], acc[ni], 0, 0, 0);

    if (have){
      int nxt = cur ^ 1;
      *(bf8s*)(&As[nxt][ra*72 + cb])      = na0;
      *(bf8s*)(&As[nxt][ra*72 + cb + 32]) = na1;
      *(bf8s*)(&Bs[nxt][ra*72 + cb])      = nb0;
      *(bf8s*)(&Bs[nxt][ra*72 + cb + 32]) = nb1;
    }
    __syncthreads();
  }

  #pragma unroll
  for (int ni = 0; ni < 4; ni++){
    int n = tile_n + ni*16 + l15;
    float bs = (epi == 6 && n >= Npost) ? 0.f : bias[n];
    #pragma unroll
    for (int r = 0; r < 4; r++){
      int m = tile_m + w*16 + q*4 + r;
      gemm_epilogue(acc[ni][r] + bs, m, n, N, epi, t0, Npost,
                    Cv, res, gate, bn_w, bn_b, bn_m, bn_v, HH, WW);
    }
  }
}

// ---- neighborhood attention: one THREAD per (token, head) ----
__global__ __launch_bounds__(256)
void k_attn(const bft* __restrict__ qkv, const float* __restrict__ rpb,
            bft* __restrict__ o, int Hh, int Ww, int d)
{
  int gid  = blockIdx.x*256 + threadIdx.x;
  int head = gid & 7;
  int t    = gid >> 3;
  int j = t % Ww; int i = (t / Ww) % Hh;
  int base = (t / (Ww*Hh)) * Hh * Ww;

  const bft* qp = qkv + (size_t)t*768 + head*32;
  float q[32];
  #pragma unroll
  for (int u = 0; u < 4; u++){
    bf8s qv = *(const bf8s*)(qp + u*8);
    #pragma unroll
    for (int e = 0; e < 8; e++) q[u*8+e] = bs2f(qv[e]);
  }

  int is = win_start(i, Hh, d), js = win_start(j, Ww, d);
  int bi = pb_start(i, Hh, d), bj = pb_start(j, Ww, d);

  float logits[25];
  int tns[25];
  #pragma unroll
  for (int x = 0; x < 5; x++){
    int rowb = base + (is + x*d)*Ww;
    #pragma unroll
    for (int y = 0; y < 5; y++){
      int tn = rowb + js + y*d;
      tns[x*5+y] = tn;
      const bft* kp = qkv + (size_t)tn*768 + 256 + head*32;
      float s = 0.f;
      #pragma unroll
      for (int u = 0; u < 4; u++){
        bf8s kv = *(const bf8s*)(kp + u*8);
        #pragma unroll
        for (int e = 0; e < 8; e++) s += q[u*8+e] * bs2f(kv[e]);
      }
      logits[x*5+y] = s + rpb[head*81 + (bi + x)*9 + (bj + y)];
    }
  }

  float mx = logits[0];
  #pragma unroll
  for (int p = 1; p < 25; p++) mx = fmaxf(mx, logits[p]);
  float ssum = 0.f;
  #pragma unroll
  for (int p = 0; p < 25; p++){ float e = __expf(logits[p] - mx); logits[p] = e; ssum += e; }
  float inv = 1.f / ssum;

  float acc[32];
  #pragma unroll
  for (int e = 0; e < 32; e++) acc[e] = 0.f;
  #pragma unroll
  for (int p = 0; p < 25; p++){
    float wgt = logits[p] * inv;
    const bft* vp = qkv + (size_t)tns[p]*768 + 512 + head*32;
    #pragma unroll
    for (int u = 0; u < 4; u++){
      bf8s vv = *(const bf8s*)(vp + u*8);
      #pragma unroll
      for (int e = 0; e < 8; e++) acc[u*8+e] += wgt * bs2f(vv[e]);
    }
  }

  bft* op = o + (size_t)t*256 + head*32;
  #pragma unroll
  for (int u = 0; u < 4; u++){
    bf8s ov;
    #pragma unroll
    for (int e = 0; e < 8; e++){
      bft h = __float2bfloat16(acc[u*8+e]);
      union { bft b; short s; } cv; cv.b = h;
      ov[e] = cv.s;
    }
    *(bf8s*)(op + u*8) = ov;
  }
}

// ---- fuse-cat: A[t][0..255]=feat(NCHW f32), A[t][256..511]=bilinear(Xprev) ----
__global__ __launch_bounds__(256)
void k_fusecat(const float* __restrict__ feat, const float* __restrict__ xprev,
               bft* __restrict__ out, int h, int w, int H2, int W2)
{
  int t = blockIdx.x; int c = threadIdx.x;
  int x = t % W2; int y = (t / W2) % H2; int b = t / (W2*H2);
  out[(size_t)t*512 + c] = __float2bfloat16(feat[(((size_t)b*256 + c)*H2 + y)*W2 + x]);
  float fy = (float)y * (float)(h-1) / (float)(H2-1);
  float fx = (float)x * (float)(w-1) / (float)(W2-1);
  int y0 = (int)floorf(fy); int y1 = min(y0+1, h-1); float wy = fy - (float)y0;
  int x0 = (int)floorf(fx); int x1 = min(x0+1, w-1); float wx = fx - (float)x0;
  const float* basep = xprev + (size_t)b*h*w*256;
  float a  = basep[((size_t)y0*w + x0)*256 + c];
  float bb = basep[((size_t)y0*w + x1)*256 + c];
  float cc = basep[((size_t)y1*w + x0)*256 + c];
  float e  = basep[((size_t)y1*w + x1)*256 + c];
  float u = a*(1.f-wy)*(1.f-wx) + bb*(1.f-wy)*wx + cc*wy*(1.f-wx) + e*wy*wx;
  out[(size_t)t*512 + 256 + c] = __float2bfloat16(u);
}

extern "C" void kernel_launch(void* const* d_in, const int* in_sizes, int n_in,
                              void* d_out, int out_size, void* d_ws, size_t ws_size,
                              hipStream_t stream)
{
  (void)in_sizes; (void)n_in; (void)out_size; (void)ws_size;
  const float* x0     = (const float*)d_in[0];
  const float* x1     = (const float*)d_in[1];
  const float* x2     = (const float*)d_in[2];
  const float* x3     = (const float*)d_in[3];
  const float* ln1_w  = (const float*)d_in[4];
  const float* ln1_b  = (const float*)d_in[5];
  const float* qkv_w  = (const float*)d_in[6];
  const float* qkv_b  = (const float*)d_in[7];
  const float* rpb    = (const float*)d_in[8];
  const float* proj_w = (const float*)d_in[9];
  const float* proj_b = (const float*)d_in[10];
  const float* ln2_w  = (const float*)d_in[11];
  const float* ln2_b  = (const float*)d_in[12];
  const float* fc1_w  = (const float*)d_in[13];
  const float* fc1_b  = (const float*)d_in[14];
  const float* fc2_w  = (const float*)d_in[15];
  const float* fc2_b  = (const float*)d_in[16];
  const float* g1     = (const float*)d_in[17];
  const float* g2     = (const float*)d_in[18];
  const float* fuse_w = (const float*)d_in[19];
  const float* fuse_b = (const float*)d_in[20];
  const float* fbn_w  = (const float*)d_in[21];
  const float* fbn_b  = (const float*)d_in[22];
  const float* fbn_m  = (const float*)d_in[23];
  const float* fbn_v  = (const float*)d_in[24];
  const float* lc1_w  = (const float*)d_in[25];
  const float* lc1_b  = (const float*)d_in[26];
  const float* lbn1_w = (const float*)d_in[27];
  const float* lbn1_b = (const float*)d_in[28];
  const float* lbn1_m = (const float*)d_in[29];
  const float* lbn1_v = (const float*)d_in[30];
  const float* lc2_w  = (const float*)d_in[31];
  const float* lc2_b  = (const float*)d_in[32];
  const float* lbn2_w = (const float*)d_in[33];
  const float* lbn2_b = (const float*)d_in[34];
  const float* lbn2_m = (const float*)d_in[35];
  const float* lbn2_v = (const float*)d_in[36];

  // ---- workspace layout (bytes), total 65,470,464 (<= proven 75.5 MB) ----
  char* ws = (char*)d_ws;
  float* X  = (float*)ws;                      // 12,582,912
  bft*   B1 = (bft*)(ws + 12582912);           //  6,291,456
  bft*   B2 = (bft*)(ws + 18874368);           // 25,165,824
  bft*   IM = B2;                              // fuse-cat buffer aliases B2
  bft*   WB = (bft*)(ws + 44040192);           // static weights (14,548,992)
  bft*   Xb = (bft*)(ws + 58589184);           // conv1 input bf16 (6,291,456)
  bft*   W_C2 = (bft*)(ws + 64880640);         // 128*2304 bf16 (589,824)

  bft* W_NAT  = WB;                            // 8 * 786432
  bft* W_FUSE = WB + 6291456;                  // 3 * 131072
  bft* W_C1   = WB + 6684672;                  // 256*2304

  // upfront weight conversion
  k_cvt_nat<<<2048, 256, 0, stream>>>(qkv_w, proj_w, fc1_w, fc2_w, W_NAT);
  k_cvt<<<512, 256, 0, stream>>>(fuse_w, 393216, W_FUSE);
  k_repack<<<256, 256, 0, stream>>>(lc1_w, W_C1, 256);
  k_repack<<<128, 256, 0, stream>>>(lc2_w, W_C2, 17);

  auto gemm = [&](const bft* A, const bft* W, const float* bias, void* C,
                  int Mloc, int N, int K, int epi, int tap, int t0, int Npost,
                  const float* res, const float* gate,
                  const float* bw, const float* bb, const float* bm, const float* bv,
                  int HH, int WW){
    if (Mloc == 12288 && N >= 768){
      dim3 g(N/128, Mloc/128);
      k_gemm128<<<g, 256, 0, stream>>>(A, W, bias, C, N, K, epi, t0, Npost,
                                       res, gate, bw, bb, bm, bv, HH, WW);
    } else {
      dim3 g(N/64, Mloc/64);
      k_gemm64L<<<g, 256, 0, stream>>>(A, W, bias, C, N, K, epi, tap, t0, Npost,
                                       res, gate, bw, bb, bm, bv, HH, WW);
    }
  };

  auto nat = [&](int l, int d, int Hh, int Ww){
    int T = 4*Hh*Ww;
    bft* wQKV  = W_NAT + (size_t)l*786432;
    bft* wPROJ = wQKV + 196608;
    bft* wFC1  = wQKV + 262144;
    bft* wFC2  = wQKV + 524288;
    k_ln<<<T, 256, 0, stream>>>(X, ln1_w + l*256, ln1_b + l*256, B1);
    gemm(B1, wQKV, qkv_b + l*768, B2, T, 768, 256, 1, 0, 0, 0,
         nullptr, nullptr, nullptr, nullptr, nullptr, nullptr, 0, 0);
    k_attn<<<T*8/256, 256, 0, stream>>>(B2, rpb + l*648, B1, Hh, Ww, d);
    gemm(B1, wPROJ, proj_b + l*256, X, T, 256, 256, 3, 0, 0, 0,
         X, g1 + l*256, nullptr, nullptr, nullptr, nullptr, 0, 0);
    k_ln<<<T, 256, 0, stream>>>(X, ln2_w + l*256, ln2_b + l*256, B1);
    gemm(B1, wFC1, fc1_b + l*1024, B2, T, 1024, 256, 2, 0, 0, 0,
         nullptr, nullptr, nullptr, nullptr, nullptr, nullptr, 0, 0);
    if (l == 7){
      // final layer: residual+gate straight to bf16 conv input
      gemm(B2, wFC2, fc2_b + l*256, Xb, T, 256, 1024, 7, 0, 0, 0,
           X, g2 + l*256, nullptr, nullptr, nullptr, nullptr, 0, 0);
    } else {
      gemm(B2, wFC2, fc2_b + l*256, X, T, 256, 1024, 3, 0, 0, 0,
           X, g2 + l*256, nullptr, nullptr, nullptr, nullptr, 0, 0);
    }
  };

  auto fuse = [&](int i, const float* feat, int h, int w, int H2, int W2){
    int Tn = 4*H2*W2;
    k_fusecat<<<Tn, 256, 0, stream>>>(feat, X, IM, h, w, H2, W2);
    gemm(IM, W_FUSE + (size_t)i*131072, fuse_b + i*256, X, Tn, 256, 512, 4, 0, 0, 0,
         nullptr, nullptr, fbn_w + i*256, fbn_b + i*256, fbn_m + i*256, fbn_v + i*256, 0, 0);
  };

  // level 3: 8x6
  k_nchw2nhwc<<<4*8*6, 256, 0, stream>>>(x3, X, 8, 6);
  nat(0, 1, 8, 6);
  nat(1, 1, 8, 6);
  fuse(0, x2, 8, 6, 16, 12);
  // level 2: 16x12
  nat(2, 2, 16, 12);
  nat(3, 2, 16, 12);
  fuse(1, x1, 16, 12, 32, 24);
  // level 1: 32x24
  nat(4, 4, 32, 24);
  nat(5, 4, 32, 24);
  fuse(2, x0, 32, 24, 64, 48);
  // level 0: 64x48
  nat(6, 8, 64, 48);
  nat(7, 8, 64, 48);   // fc2 writes Xb (bf16) via epi 7

  // ---- convs: implicit-im2col MFMA GEMMs (64-tile, high grid) ----
  // conv1: M=12288, N=256, K=2304, tap from Xb -> B1 (bf16 NHWC), grid 768
  gemm(Xb, W_C1, lc1_b, B1, 12288, 256, 2304, 5, 1, 0, 0,
       nullptr, nullptr, lbn1_w, lbn1_b, lbn1_m, lbn1_v, 64, 48);
  // conv2: M=12288, N=128(pad), K=2304, tap from B1 -> d_out f32 NCHW, grid 384
  gemm(B1, W_C2, lc2_b, d_out, 12288, 128, 2304, 6, 1, 0, 17,
       nullptr, nullptr, lbn2_w, lbn2_b, lbn2_m, lbn2_v, 64, 48);
}

// Round 7
// 1016.720 us; speedup vs baseline: 1.7310x; 1.1642x over previous
//
#include <hip/hip_runtime.h>
#include <hip/hip_bf16.h>

typedef __hip_bfloat16 bft;
typedef short bf8s __attribute__((ext_vector_type(8)));   // 8 bf16 (4 VGPRs)
typedef float f4 __attribute__((ext_vector_type(4)));

#define KW 5
#define NSW 2
#define EPS 1e-5f
#define BSTRIDE 270   // shorts per B-row in LDS (256 data + 14 pad)

__device__ __forceinline__ float bs2f(short s){
  union { unsigned u; float f; } v; v.u = ((unsigned)(unsigned short)s) << 16; return v.f;
}

__device__ __forceinline__ int win_start(int i, int L, int d){
  if (d <= 1){
    int s = i - NSW; if (s < 0) s = 0;
    if (i + NSW >= L) s += L - i - NSW - 1;
    return s;
  }
  int ni = i - NSW*d;
  if (ni < 0) return i % d;
  if (i + NSW*d >= L){
    int imodd = i % d;
    int a = (L / d) * d;
    int b = L - a;
    if (imodd < b) return L - b + imodd - 2*NSW*d;
    return a + imodd - KW*d;
  }
  return ni;
}
__device__ __forceinline__ int pb_start(int i, int L, int d){
  if (d <= 1){
    int s = NSW;
    if (i < NSW) s += NSW - i;
    if (i + NSW >= L) s += L - i - 1 - NSW;
    return s;
  }
  if (i - NSW*d < 0) return KW - 1 - i/d;
  if (i + NSW*d >= L) return (L - i - 1)/d;
  return NSW;
}

// ---- upfront: all 8 NAT layers' weights fp32 -> bf16, layer-contiguous ----
__global__ __launch_bounds__(256)
void k_cvt_nat(const float* __restrict__ qkv_w, const float* __restrict__ proj_w,
               const float* __restrict__ fc1_w, const float* __restrict__ fc2_w,
               bft* __restrict__ dst)
{
  for (int i = blockIdx.x*256 + threadIdx.x; i < 8*786432; i += gridDim.x*256){
    int l = i / 786432;
    int off = i - l*786432;
    float v;
    if (off < 196608) v = qkv_w[(size_t)l*196608 + off];
    else if (off < 262144) v = proj_w[(size_t)l*65536 + (off - 196608)];
    else if (off < 524288) v = fc1_w[(size_t)l*262144 + (off - 262144)];
    else v = fc2_w[(size_t)l*262144 + (off - 524288)];
    dst[i] = __float2bfloat16(v);
  }
}

__global__ __launch_bounds__(256)
void k_cvt(const float* __restrict__ src, int n, bft* __restrict__ dst)
{
  for (int i = blockIdx.x*256 + threadIdx.x; i < n; i += gridDim.x*256)
    dst[i] = __float2bfloat16(src[i]);
}

// ---- conv weight repack: OIHW fp32 -> [o][tap*256+c] bf16 (o padded) ----
__global__ __launch_bounds__(256)
void k_repack(const float* __restrict__ in, bft* __restrict__ out, int O_in)
{
  int o = blockIdx.x, c = threadIdx.x;
  #pragma unroll
  for (int tap = 0; tap < 9; tap++){
    float v = (o < O_in) ? in[((size_t)(o*256 + c))*9 + tap] : 0.f;
    out[(size_t)o*2304 + tap*256 + c] = __float2bfloat16(v);
  }
}

// ---- NCHW -> NHWC (f32) ----
__global__ __launch_bounds__(256)
void k_nchw2nhwc(const float* __restrict__ in, float* __restrict__ out,
                 int H, int W){
  int t = blockIdx.x; int c = threadIdx.x;
  int x = t % W; int y = (t / W) % H; int b = t / (W*H);
  out[(size_t)t*256 + c] = in[(((size_t)b*256 + c)*H + y)*W + x];
}

// ---- LayerNorm (C=256), one block per token; fp32 in, bf16 out ----
__global__ __launch_bounds__(256)
void k_ln(const float* __restrict__ x, const float* __restrict__ w,
          const float* __restrict__ b, bft* __restrict__ out)
{
  __shared__ float red[4];
  __shared__ float stats[2];
  int t = blockIdx.x, c = threadIdx.x;
  float v = x[(size_t)t*256 + c];
  float s = v;
  #pragma unroll
  for (int m = 32; m >= 1; m >>= 1) s += __shfl_xor(s, m, 64);
  int wave = c >> 6;
  if ((c & 63) == 0) red[wave] = s;
  __syncthreads();
  if (c == 0) stats[0] = (red[0]+red[1]+red[2]+red[3]) * (1.f/256.f);
  __syncthreads();
  float mean = stats[0];
  float dd = v - mean;
  float s2 = dd*dd;
  #pragma unroll
  for (int m = 32; m >= 1; m >>= 1) s2 += __shfl_xor(s2, m, 64);
  if ((c & 63) == 0) red[wave] = s2;
  __syncthreads();
  if (c == 0) stats[1] = (red[0]+red[1]+red[2]+red[3]) * (1.f/256.f);
  __syncthreads();
  float var = stats[1];
  out[(size_t)t*256 + c] = __float2bfloat16(dd * rsqrtf(var + EPS) * w[c] + b[c]);
}

// ======== shared epilogue ========
// epi: 1 qkv-scale(n<256)->bf16; 2 gelu->bf16; 3 res+gate->f32;
//      4 fuse-BN->f32; 5 conv-BN+ReLU->bf16; 6 conv-BN+ReLU->f32 NCHW (n<Npost);
//      7 res+gate->bf16
__device__ __forceinline__ void gemm_epilogue(
    float v, int m, int n, int N, int epi, int t0, int Npost,
    void* Cv, const float* res, const float* gate,
    const float* bn_w, const float* bn_b, const float* bn_m, const float* bn_v,
    int HH, int WW)
{
  if (epi == 1){
    if (n < 256) v *= 0.17677669529663689f;
    ((bft*)Cv)[(size_t)m*N + n] = __float2bfloat16(v);
  } else if (epi == 2){
    v = 0.5f*v*(1.f + erff(v*0.70710678118654752f));
    ((bft*)Cv)[(size_t)m*N + n] = __float2bfloat16(v);
  } else if (epi == 3){
    ((float*)Cv)[(size_t)m*N + n] = res[(size_t)m*N + n] + gate[n]*v;
  } else if (epi == 4){
    float s = bn_w[n] * rsqrtf(bn_v[n] + EPS);
    ((float*)Cv)[(size_t)m*N + n] = (v - bn_m[n])*s + bn_b[n];
  } else if (epi == 5){
    float s = bn_w[n] * rsqrtf(bn_v[n] + EPS);
    float o = fmaxf((v - bn_m[n])*s + bn_b[n], 0.f);
    ((bft*)Cv)[(size_t)(t0 + m)*N + n] = __float2bfloat16(o);
  } else if (epi == 6){
    if (n < Npost){
      float s = bn_w[n] * rsqrtf(bn_v[n] + EPS);
      float o = fmaxf((v - bn_m[n])*s + bn_b[n], 0.f);
      int tok = t0 + m;
      int xx = tok % WW; int yy = (tok / WW) % HH; int bb = tok / (WW*HH);
      ((float*)Cv)[(((size_t)bb*Npost + n)*HH + yy)*WW + xx] = o;
    }
  } else { // epi == 7: residual+gate, bf16 out
    ((bft*)Cv)[(size_t)m*N + n] = __float2bfloat16(res[(size_t)m*N + n] + gate[n]*v);
  }
}

// ---- single/few-stage GEMM: 64x64 tile, BK=256, A in registers, B in LDS ----
// K must be a multiple of 256. tap=1: implicit im2col from bf16 NHWC (C=256,
// K=2304): stage s == conv tap s, SAME zero padding.
__global__ __launch_bounds__(256, 4)
void k_gemmK(const bft* __restrict__ A, const bft* __restrict__ Wt,
             const float* __restrict__ bias, void* __restrict__ Cv,
             int N, int K, int epi, int tap, int t0, int Npost,
             const float* __restrict__ res, const float* __restrict__ gate,
             const float* __restrict__ bn_w, const float* __restrict__ bn_b,
             const float* __restrict__ bn_m, const float* __restrict__ bn_v,
             int HH, int WW)
{
  __shared__ short Bs[64 * BSTRIDE];   // 34,560 B

  const int tid = threadIdx.x;
  const int tile_n = blockIdx.x * 64;
  const int tile_m = blockIdx.y * 64;
  const int w = tid >> 6, lane = tid & 63, q = lane >> 4, l15 = lane & 15;

  // A: this lane's MFMA rows, direct from global
  const int arow = tile_m + w*16 + l15;
  const bft* aptr = A + (size_t)arow * K + q*8;
  int ax = 0, ay = 0, ab = 0;
  if (tap){ ax = arow % WW; ay = (arow / WW) % HH; ab = arow / (WW*HH); }

  // B staging: thread covers row (tid>>2), chunks (tid&3)+4i, i=0..7
  const int brow = tid >> 2;
  const int bci  = tid & 3;
  const bft* bptr = Wt + (size_t)(tile_n + brow) * K + bci*8;

  f4 acc[4];
  #pragma unroll
  for (int i = 0; i < 4; i++) acc[i] = (f4){0.f,0.f,0.f,0.f};

  const int stages = K >> 8;

  for (int s = 0; s < stages; s++){
    // ---- A fragments for this stage (8 x 16B, all in flight) ----
    bf8s afr[8];
    if (!tap){
      const bft* ap = aptr + s*256;
      #pragma unroll
      for (int kc = 0; kc < 8; kc++)
        afr[kc] = *(const bf8s*)(ap + kc*32);
    } else {
      int ty = s / 3;
      int ky = ty - 1, kx = s - ty*3 - 1;
      int yy = ay + ky, xx = ax + kx;
      bool ok = (yy >= 0 && yy < HH && xx >= 0 && xx < WW);
      const bft* ap = A + ((((size_t)ab*HH + yy)*WW + xx) << 8) + q*8;
      bf8s z;
      #pragma unroll
      for (int e = 0; e < 8; e++) z[e] = 0;
      #pragma unroll
      for (int kc = 0; kc < 8; kc++)
        afr[kc] = ok ? *(const bf8s*)(ap + kc*32) : z;
    }
    // ---- B chunks (8 x 16B, all in flight) ----
    bf8s bch[8];
    {
      const bft* bp = bptr + s*256;
      #pragma unroll
      for (int i = 0; i < 8; i++)
        bch[i] = *(const bf8s*)(bp + 32*i);
    }
    if (s > 0) __syncthreads();       // previous stage's LDS reads complete
    #pragma unroll
    for (int i = 0; i < 8; i++)
      *(bf8s*)(&Bs[brow*BSTRIDE + bci*8 + 32*i]) = bch[i];
    __syncthreads();

    #pragma unroll
    for (int kc = 0; kc < 8; kc++){
      #pragma unroll
      for (int nf = 0; nf < 4; nf++){
        bf8s bfr = *(const bf8s*)(&Bs[(nf*16 + l15)*BSTRIDE + kc*32 + q*8]);
        acc[nf] = __builtin_amdgcn_mfma_f32_16x16x32_bf16(afr[kc], bfr, acc[nf], 0, 0, 0);
      }
    }
  }

  #pragma unroll
  for (int nf = 0; nf < 4; nf++){
    int n = tile_n + nf*16 + l15;
    float bs = (epi == 6 && n >= Npost) ? 0.f : bias[n];
    #pragma unroll
    for (int r = 0; r < 4; r++){
      int m = tile_m + w*16 + q*4 + r;
      gemm_epilogue(acc[nf][r] + bs, m, n, N, epi, t0, Npost,
                    Cv, res, gate, bn_w, bn_b, bn_m, bn_v, HH, WW);
    }
  }
}

// ---- neighborhood attention: one THREAD per (token, head) ----
__global__ __launch_bounds__(256)
void k_attn(const bft* __restrict__ qkv, const float* __restrict__ rpb,
            bft* __restrict__ o, int Hh, int Ww, int d)
{
  int gid  = blockIdx.x*256 + threadIdx.x;
  int head = gid & 7;
  int t    = gid >> 3;
  int j = t % Ww; int i = (t / Ww) % Hh;
  int base = (t / (Ww*Hh)) * Hh * Ww;

  const bft* qp = qkv + (size_t)t*768 + head*32;
  float q[32];
  #pragma unroll
  for (int u = 0; u < 4; u++){
    bf8s qv = *(const bf8s*)(qp + u*8);
    #pragma unroll
    for (int e = 0; e < 8; e++) q[u*8+e] = bs2f(qv[e]);
  }

  int is = win_start(i, Hh, d), js = win_start(j, Ww, d);
  int bi = pb_start(i, Hh, d), bj = pb_start(j, Ww, d);

  float logits[25];
  int tns[25];
  #pragma unroll
  for (int x = 0; x < 5; x++){
    int rowb = base + (is + x*d)*Ww;
    #pragma unroll
    for (int y = 0; y < 5; y++){
      int tn = rowb + js + y*d;
      tns[x*5+y] = tn;
      const bft* kp = qkv + (size_t)tn*768 + 256 + head*32;
      float s = 0.f;
      #pragma unroll
      for (int u = 0; u < 4; u++){
        bf8s kv = *(const bf8s*)(kp + u*8);
        #pragma unroll
        for (int e = 0; e < 8; e++) s += q[u*8+e] * bs2f(kv[e]);
      }
      logits[x*5+y] = s + rpb[head*81 + (bi + x)*9 + (bj + y)];
    }
  }

  float mx = logits[0];
  #pragma unroll
  for (int p = 1; p < 25; p++) mx = fmaxf(mx, logits[p]);
  float ssum = 0.f;
  #pragma unroll
  for (int p = 0; p < 25; p++){ float e = __expf(logits[p] - mx); logits[p] = e; ssum += e; }
  float inv = 1.f / ssum;

  float acc[32];
  #pragma unroll
  for (int e = 0; e < 32; e++) acc[e] = 0.f;
  #pragma unroll
  for (int p = 0; p < 25; p++){
    float wgt = logits[p] * inv;
    const bft* vp = qkv + (size_t)tns[p]*768 + 512 + head*32;
    #pragma unroll
    for (int u = 0; u < 4; u++){
      bf8s vv = *(const bf8s*)(vp + u*8);
      #pragma unroll
      for (int e = 0; e < 8; e++) acc[u*8+e] += wgt * bs2f(vv[e]);
    }
  }

  bft* op = o + (size_t)t*256 + head*32;
  #pragma unroll
  for (int u = 0; u < 4; u++){
    bf8s ov;
    #pragma unroll
    for (int e = 0; e < 8; e++){
      bft h = __float2bfloat16(acc[u*8+e]);
      union { bft b; short s; } cv; cv.b = h;
      ov[e] = cv.s;
    }
    *(bf8s*)(op + u*8) = ov;
  }
}

// ---- fuse-cat: A[t][0..255]=feat(NCHW f32), A[t][256..511]=bilinear(Xprev) ----
__global__ __launch_bounds__(256)
void k_fusecat(const float* __restrict__ feat, const float* __restrict__ xprev,
               bft* __restrict__ out, int h, int w, int H2, int W2)
{
  int t = blockIdx.x; int c = threadIdx.x;
  int x = t % W2; int y = (t / W2) % H2; int b = t / (W2*H2);
  out[(size_t)t*512 + c] = __float2bfloat16(feat[(((size_t)b*256 + c)*H2 + y)*W2 + x]);
  float fy = (float)y * (float)(h-1) / (float)(H2-1);
  float fx = (float)x * (float)(w-1) / (float)(W2-1);
  int y0 = (int)floorf(fy); int y1 = min(y0+1, h-1); float wy = fy - (float)y0;
  int x0 = (int)floorf(fx); int x1 = min(x0+1, w-1); float wx = fx - (float)x0;
  const float* basep = xprev + (size_t)b*h*w*256;
  float a  = basep[((size_t)y0*w + x0)*256 + c];
  float bb = basep[((size_t)y0*w + x1)*256 + c];
  float cc = basep[((size_t)y1*w + x0)*256 + c];
  float e  = basep[((size_t)y1*w + x1)*256 + c];
  float u = a*(1.f-wy)*(1.f-wx) + bb*(1.f-wy)*wx + cc*wy*(1.f-wx) + e*wy*wx;
  out[(size_t)t*512 + 256 + c] = __float2bfloat16(u);
}

extern "C" void kernel_launch(void* const* d_in, const int* in_sizes, int n_in,
                              void* d_out, int out_size, void* d_ws, size_t ws_size,
                              hipStream_t stream)
{
  (void)in_sizes; (void)n_in; (void)out_size; (void)ws_size;
  const float* x0     = (const float*)d_in[0];
  const float* x1     = (const float*)d_in[1];
  const float* x2     = (const float*)d_in[2];
  const float* x3     = (const float*)d_in[3];
  const float* ln1_w  = (const float*)d_in[4];
  const float* ln1_b  = (const float*)d_in[5];
  const float* qkv_w  = (const float*)d_in[6];
  const float* qkv_b  = (const float*)d_in[7];
  const float* rpb    = (const float*)d_in[8];
  const float* proj_w = (const float*)d_in[9];
  const float* proj_b = (const float*)d_in[10];
  const float* ln2_w  = (const float*)d_in[11];
  const float* ln2_b  = (const float*)d_in[12];
  const float* fc1_w  = (const float*)d_in[13];
  const float* fc1_b  = (const float*)d_in[14];
  const float* fc2_w  = (const float*)d_in[15];
  const float* fc2_b  = (const float*)d_in[16];
  const float* g1     = (const float*)d_in[17];
  const float* g2     = (const float*)d_in[18];
  const float* fuse_w = (const float*)d_in[19];
  const float* fuse_b = (const float*)d_in[20];
  const float* fbn_w  = (const float*)d_in[21];
  const float* fbn_b  = (const float*)d_in[22];
  const float* fbn_m  = (const float*)d_in[23];
  const float* fbn_v  = (const float*)d_in[24];
  const float* lc1_w  = (const float*)d_in[25];
  const float* lc1_b  = (const float*)d_in[26];
  const float* lbn1_w = (const float*)d_in[27];
  const float* lbn1_b = (const float*)d_in[28];
  const float* lbn1_m = (const float*)d_in[29];
  const float* lbn1_v = (const float*)d_in[30];
  const float* lc2_w  = (const float*)d_in[31];
  const float* lc2_b  = (const float*)d_in[32];
  const float* lbn2_w = (const float*)d_in[33];
  const float* lbn2_b = (const float*)d_in[34];
  const float* lbn2_m = (const float*)d_in[35];
  const float* lbn2_v = (const float*)d_in[36];

  // ---- workspace layout (bytes), total 65,470,464 (<= proven 75.5 MB) ----
  char* ws = (char*)d_ws;
  float* X  = (float*)ws;                      // 12,582,912
  bft*   B1 = (bft*)(ws + 12582912);           //  6,291,456
  bft*   B2 = (bft*)(ws + 18874368);           // 25,165,824
  bft*   IM = B2;                              // fuse-cat buffer aliases B2
  bft*   WB = (bft*)(ws + 44040192);           // static weights (14,548,992)
  bft*   Xb = (bft*)(ws + 58589184);           // conv1 input bf16 (6,291,456)
  bft*   W_C2 = (bft*)(ws + 64880640);         // 128*2304 bf16 (589,824)

  bft* W_NAT  = WB;                            // 8 * 786432
  bft* W_FUSE = WB + 6291456;                  // 3 * 131072
  bft* W_C1   = WB + 6684672;                  // 256*2304

  // upfront weight conversion
  k_cvt_nat<<<2048, 256, 0, stream>>>(qkv_w, proj_w, fc1_w, fc2_w, W_NAT);
  k_cvt<<<512, 256, 0, stream>>>(fuse_w, 393216, W_FUSE);
  k_repack<<<256, 256, 0, stream>>>(lc1_w, W_C1, 256);
  k_repack<<<128, 256, 0, stream>>>(lc2_w, W_C2, 17);

  auto gemm = [&](const bft* A, const bft* W, const float* bias, void* C,
                  int Mloc, int N, int K, int epi, int tap, int t0, int Npost,
                  const float* res, const float* gate,
                  const float* bw, const float* bb, const float* bm, const float* bv,
                  int HH, int WW){
    dim3 g(N/64, Mloc/64);
    k_gemmK<<<g, 256, 0, stream>>>(A, W, bias, C, N, K, epi, tap, t0, Npost,
                                   res, gate, bw, bb, bm, bv, HH, WW);
  };

  auto nat = [&](int l, int d, int Hh, int Ww){
    int T = 4*Hh*Ww;
    bft* wQKV  = W_NAT + (size_t)l*786432;
    bft* wPROJ = wQKV + 196608;
    bft* wFC1  = wQKV + 262144;
    bft* wFC2  = wQKV + 524288;
    k_ln<<<T, 256, 0, stream>>>(X, ln1_w + l*256, ln1_b + l*256, B1);
    gemm(B1, wQKV, qkv_b + l*768, B2, T, 768, 256, 1, 0, 0, 0,
         nullptr, nullptr, nullptr, nullptr, nullptr, nullptr, 0, 0);
    k_attn<<<T*8/256, 256, 0, stream>>>(B2, rpb + l*648, B1, Hh, Ww, d);
    gemm(B1, wPROJ, proj_b + l*256, X, T, 256, 256, 3, 0, 0, 0,
         X, g1 + l*256, nullptr, nullptr, nullptr, nullptr, 0, 0);
    k_ln<<<T, 256, 0, stream>>>(X, ln2_w + l*256, ln2_b + l*256, B1);
    gemm(B1, wFC1, fc1_b + l*1024, B2, T, 1024, 256, 2, 0, 0, 0,
         nullptr, nullptr, nullptr, nullptr, nullptr, nullptr, 0, 0);
    if (l == 7){
      gemm(B2, wFC2, fc2_b + l*256, Xb, T, 256, 1024, 7, 0, 0, 0,
           X, g2 + l*256, nullptr, nullptr, nullptr, nullptr, 0, 0);
    } else {
      gemm(B2, wFC2, fc2_b + l*256, X, T, 256, 1024, 3, 0, 0, 0,
           X, g2 + l*256, nullptr, nullptr, nullptr, nullptr, 0, 0);
    }
  };

  auto fuse = [&](int i, const float* feat, int h, int w, int H2, int W2){
    int Tn = 4*H2*W2;
    k_fusecat<<<Tn, 256, 0, stream>>>(feat, X, IM, h, w, H2, W2);
    gemm(IM, W_FUSE + (size_t)i*131072, fuse_b + i*256, X, Tn, 256, 512, 4, 0, 0, 0,
         nullptr, nullptr, fbn_w + i*256, fbn_b + i*256, fbn_m + i*256, fbn_v + i*256, 0, 0);
  };

  // level 3: 8x6
  k_nchw2nhwc<<<4*8*6, 256, 0, stream>>>(x3, X, 8, 6);
  nat(0, 1, 8, 6);
  nat(1, 1, 8, 6);
  fuse(0, x2, 8, 6, 16, 12);
  // level 2: 16x12
  nat(2, 2, 16, 12);
  nat(3, 2, 16, 12);
  fuse(1, x1, 16, 12, 32, 24);
  // level 1: 32x24
  nat(4, 4, 32, 24);
  nat(5, 4, 32, 24);
  fuse(2, x0, 32, 24, 64, 48);
  // level 0: 64x48
  nat(6, 8, 64, 48);
  nat(7, 8, 64, 48);   // fc2 writes Xb (bf16) via epi 7

  // ---- convs: implicit-im2col (tap-mode), one dispatch each ----
  // conv1: M=12288, N=256, K=2304 (9 stages) from Xb -> B1 (bf16 NHWC)
  gemm(Xb, W_C1, lc1_b, B1, 12288, 256, 2304, 5, 1, 0, 0,
       nullptr, nullptr, lbn1_w, lbn1_b, lbn1_m, lbn1_v, 64, 48);
  // conv2: M=12288, N=128(pad), K=2304 from B1 -> d_out f32 NCHW (n<17)
  gemm(B1, W_C2, lc2_b, d_out, 12288, 128, 2304, 6, 1, 0, 17,
       nullptr, nullptr, lbn2_w, lbn2_b, lbn2_m, lbn2_v, 64, 48);
}